// Round 6
// baseline (423.300 us; speedup 1.0000x reference)
//
#include <hip/hip_runtime.h>
#include <stdint.h>

#define N_B 8
#define A_N 131072
#define T_N 64
#define NUM_TRAIN 256
#define NEG_TAU 0.05f
#define ITEM_CAP 1024
#define APT 4
#define GBLK 128                   // k_main/k_final blocks per batch
#define SEG 1024                   // candidate segment per block (= anchors per block)

typedef unsigned long long u64;
typedef unsigned int u32;

// IoU exactly matching the reference op sequence (no FMA contraction).
__device__ __forceinline__ float iou_one(float ay1, float ax1, float ay2, float ax2,
                                         float a_area, float gy1, float gx1, float gy2,
                                         float gx2, float g_area) {
#pragma clang fp contract(off)
    float ih = fmaxf(fminf(ay2, gy2) - fmaxf(ay1, gy1), 0.0f);
    float iw = fmaxf(fminf(ax2, gx2) - fmaxf(ax1, gx1), 0.0f);
    float inter = ih * iw;
    float uni = (a_area + g_area) - inter;
    return uni > 0.0f ? inter / uni : 0.0f;
}

// ============ k_main: IoU pass + preclass + column partials + candidate segments ============
__global__ void __launch_bounds__(256, 4) k_main(const float4* __restrict__ anchors4,
                                                 const float4* __restrict__ gts4,
                                                 const float* __restrict__ rpos,
                                                 const float* __restrict__ rneg,
                                                 unsigned char* __restrict__ preclass,
                                                 u64* __restrict__ colpart,
                                                 u64* __restrict__ pos_list,
                                                 u64* __restrict__ neg_list,
                                                 int* __restrict__ bcp, int* __restrict__ bcn) {
    __shared__ float4 gbox[T_N];
    __shared__ float gars[T_N];
    __shared__ u64 cmax[T_N];
    __shared__ int lp, ln;
    int n = blockIdx.y, bx = blockIdx.x, tid = threadIdx.x, lane = tid & 63;
    int a0 = bx * SEG + tid;
    size_t nA = (size_t)n * A_N;

    if (tid < T_N) {
        float4 gb = gts4[n * T_N + tid];
        gbox[tid] = gb;
        {
#pragma clang fp contract(off)
            gars[tid] = (gb.z - gb.x) * (gb.w - gb.y);
        }
        cmax[tid] = 0;   // any pack (v<<32)|~a is > 0
    }
    if (tid == 0) { lp = 0; ln = 0; }
    __syncthreads();

    float ay1[APT], ax1[APT], ay2[APT], ax2[APT], aar[APT], vmax[APT];
#pragma unroll
    for (int k = 0; k < APT; k++) {
        float4 ab = anchors4[nA + a0 + k * 256];
        float y1 = ab.x, x1 = ab.y, y2 = ab.z, x2 = ab.w;
        bool inb = (y1 >= 0.f) && (x1 >= 0.f) && (y2 <= 1.f) && (x2 <= 1.f);
        if (!inb) { y1 = x1 = y2 = x2 = 0.f; }
        ay1[k] = y1; ax1[k] = x1; ay2[k] = y2; ax2[k] = x2;
        {
#pragma clang fp contract(off)
            aar[k] = (y2 - y1) * (x2 - x1);
        }
        vmax[k] = 0.f;
    }

#pragma unroll 4
    for (int jj = 0; jj < T_N; jj++) {
        int j = (lane + jj) & (T_N - 1);   // lane-staggered: distinct cmax[j] per lane
        float4 gb = gbox[j];
        float gar = gars[j];
        // k=0 seeds the per-thread column winner; strict > keeps smallest k (= smallest anchor)
        float vb = iou_one(ay1[0], ax1[0], ay2[0], ax2[0], aar[0], gb.x, gb.y, gb.z, gb.w, gar);
        vmax[0] = fmaxf(vmax[0], vb);
        int kb = 0;
#pragma unroll
        for (int k = 1; k < APT; k++) {
            float v = iou_one(ay1[k], ax1[k], ay2[k], ax2[k], aar[k], gb.x, gb.y, gb.z, gb.w, gar);
            vmax[k] = fmaxf(vmax[k], v);
            if (v > vb) { vb = v; kb = k; }
        }
        u64 pk = ((u64)__float_as_uint(vb) << 32) | (u32)(~(u32)(a0 + (kb << 8)));
        atomicMax(&cmax[j], pk);   // fire-and-forget, no same-address contention in-wave
    }

    size_t segbase = ((size_t)(n * GBLK + bx)) << 10;
#pragma unroll
    for (int k = 0; k < APT; k++) {
        int a = a0 + k * 256;
        float vm = vmax[k];
        int c0 = (vm < 0.3f) ? 0 : ((vm >= 0.7f) ? 1 : -1);
        preclass[nA + a] = (unsigned char)(signed char)c0;
        if (c0 == 1) {
            int s = atomicAdd(&lp, 1);
            pos_list[segbase + s] = ((u64)__float_as_uint(rpos[nA + a]) << 32) | (u32)a;
        } else if (c0 == 0) {
            float r = rneg[nA + a];
            if (r < NEG_TAU) {
                int s = atomicAdd(&ln, 1);
                neg_list[segbase + s] = ((u64)__float_as_uint(r) << 32) | (u32)a;
            }
        }
    }
    __syncthreads();
    if (tid < T_N) colpart[(size_t)((n << 6) + tid) * GBLK + bx] = cmax[tid];
    if (tid == 0) { bcp[n * GBLK + bx] = lp; bcn[n * GBLK + bx] = ln; }
}

// ============ segmented exact k-th smallest (0-indexed), optional extras / exclusion ============
__device__ u64 select_seg(const u64* lists, const int* scnt, int nseg,
                          const u64* extras, int ecnt, const int* excl,
                          int k, float scale, u64 ovf_all,
                          int* hist, u64* items, int* misc, int* wsum, u64* result) {
    int tid = threadIdx.x, lane = tid & 63, wid = tid >> 6;
    hist[tid] = 0;
    if (tid == 0) { misc[0] = 0; *result = ovf_all; }
    __syncthreads();

    for (int blk = 0; blk < nseg; blk++) {
        int c = scnt[blk];
        const u64* b = lists + ((size_t)blk << 10);
        for (int i = tid; i < c; i += 256) {
            u64 p = b[i];
            if (excl) {
                int a = (int)(u32)p;
                bool ex = false;
                for (int t = 0; t < T_N; t++) ex |= (excl[t] == a);
                if (ex) continue;
            }
            float v = __uint_as_float((u32)(p >> 32));
            int bb = (int)(v * scale); bb = bb > 255 ? 255 : bb;
            atomicAdd(&hist[bb], 1);
        }
    }
    for (int i = tid; i < ecnt; i += 256) {
        float v = __uint_as_float((u32)(extras[i] >> 32));
        int bb = (int)(v * scale); bb = bb > 255 ? 255 : bb;
        atomicAdd(&hist[bb], 1);
    }
    __syncthreads();

    int h = hist[tid], v = h;
#pragma unroll
    for (int d = 1; d < 64; d <<= 1) {
        int t = __shfl_up(v, d, 64);
        if (lane >= d) v += t;
    }
    if (lane == 63) wsum[wid] = v;
    __syncthreads();
    int base = 0;
    for (int w = 0; w < wid; w++) base += wsum[w];
    int total = wsum[0] + wsum[1] + wsum[2] + wsum[3];
    int incl = base + v, exc = incl - h;
    if (k >= exc && k < incl) { misc[1] = tid; misc[2] = exc; }
    __syncthreads();
    if (k >= total) return ovf_all;   // keep-all case (uniform across block)
    int b = misc[1], before = misc[2];

    for (int blk = 0; blk < nseg; blk++) {
        int c = scnt[blk];
        const u64* bb2 = lists + ((size_t)blk << 10);
        for (int i = tid; i < c; i += 256) {
            u64 p = bb2[i];
            if (excl) {
                int a = (int)(u32)p;
                bool ex = false;
                for (int t = 0; t < T_N; t++) ex |= (excl[t] == a);
                if (ex) continue;
            }
            float vv = __uint_as_float((u32)(p >> 32));
            int bn = (int)(vv * scale); bn = bn > 255 ? 255 : bn;
            if (bn == b) { int ix = atomicAdd(&misc[0], 1); if (ix < ITEM_CAP) items[ix] = p; }
        }
    }
    for (int i = tid; i < ecnt; i += 256) {
        u64 p = extras[i];
        float vv = __uint_as_float((u32)(p >> 32));
        int bn = (int)(vv * scale); bn = bn > 255 ? 255 : bn;
        if (bn == b) { int ix = atomicAdd(&misc[0], 1); if (ix < ITEM_CAP) items[ix] = p; }
    }
    __syncthreads();
    int m = misc[0]; m = m < ITEM_CAP ? m : ITEM_CAP;
    int target = k - before;
    for (int i = tid; i < m; i += 256) {
        u64 p = items[i];
        int r = 0;
        for (int j = 0; j < m; j++) r += (items[j] < p);
        if (r == target) *result = p;
    }
    __syncthreads();
    u64 res = *result;
    __syncthreads();
    return res;
}

// ============ k_select: colred + winner extras/exclusion + both cutoffs (one block/batch) ======
__global__ void __launch_bounds__(256) k_select(const u64* __restrict__ pos_list,
                                                const u64* __restrict__ neg_list,
                                                const int* __restrict__ bcp,
                                                const int* __restrict__ bcn,
                                                const u64* __restrict__ colpart,
                                                const unsigned char* __restrict__ preclass,
                                                const float* __restrict__ rpos,
                                                int* __restrict__ wnr_g,
                                                u64* __restrict__ cutoff) {
    __shared__ int sbp[GBLK], sbn[GBLK];
    __shared__ u64 cq[256];
    __shared__ int wnrs[T_N];
    __shared__ u64 extras[T_N];
    __shared__ int hist[256];
    __shared__ u64 items[ITEM_CAP];
    __shared__ int misc[4];
    __shared__ u64 result;
    __shared__ int wsum[4];
    __shared__ int shr[9];
    int n = blockIdx.x, tid = threadIdx.x, lane = tid & 63, wid = tid >> 6;

    int pv = tid < GBLK ? bcp[n * GBLK + tid] : 0;
    int nv = tid < GBLK ? bcn[n * GBLK + tid] : 0;
    if (tid < GBLK) { sbp[tid] = pv; sbn[tid] = nv; }
#pragma unroll
    for (int off = 32; off > 0; off >>= 1) {
        pv += __shfl_xor(pv, off, 64);
        nv += __shfl_xor(nv, off, 64);
    }
    if (lane == 0) { shr[wid] = pv; shr[4 + wid] = nv; }

    // column reduction: thread (t=tid>>2, q=tid&3) reduces 32 block-partials
    {
        int t = tid >> 2, q = tid & 3;
        const u64* cp = colpart + (size_t)((n << 6) + t) * GBLK + q * 32;
        u64 m = 0;
        for (int i = 0; i < 32; i++) { u64 x = cp[i]; m = x > m ? x : m; }
        cq[tid] = m;
    }
    __syncthreads();
    if (tid < T_N) {
        u64 m = cq[tid * 4];
        u64 x = cq[tid * 4 + 1]; m = x > m ? x : m;
        x = cq[tid * 4 + 2]; m = x > m ? x : m;
        x = cq[tid * 4 + 3]; m = x > m ? x : m;
        int w = (int)(~(u32)(m & 0xFFFFFFFFull));
        wnrs[tid] = w;
        wnr_g[n * T_N + tid] = w;
    }
    __syncthreads();
    if (tid < T_N) {   // wave 0: dedup winners, build pos extras (winners not already preclass==1)
        int w = wnrs[tid];
        bool dup = false;
        for (int t2 = 0; t2 < tid; t2++) dup |= (wnrs[t2] == w);
        int pc = (int)(signed char)preclass[(size_t)n * A_N + w];
        bool val = !dup && (pc != 1);
        u64 mask = __ballot(val);
        if (val) {
            int ix = (int)__popcll(mask & ((1ull << lane) - 1));
            extras[ix] = ((u64)__float_as_uint(rpos[(size_t)n * A_N + w]) << 32) | (u32)w;
        }
        if (tid == 0) shr[8] = (int)__popcll(mask);
    }
    __syncthreads();
    int extra_cnt = shr[8];
    int P = shr[0] + shr[1] + shr[2] + shr[3] + extra_cnt;

    u64 cpos = select_seg(pos_list + (((size_t)n * GBLK) << 10), sbp, GBLK,
                          extras, extra_cnt, nullptr,
                          NUM_TRAIN / 2, 256.0f, ~0ull,
                          hist, items, misc, wsum, &result);
    int n_pos = P < NUM_TRAIN / 2 ? P : NUM_TRAIN / 2;
    int k_neg = NUM_TRAIN - n_pos;
    u64 cneg = select_seg(neg_list + (((size_t)n * GBLK) << 10), sbn, GBLK,
                          nullptr, 0, wnrs,
                          k_neg, 256.0f / NEG_TAU, ((u64)__float_as_uint(NEG_TAU) << 32),
                          hist, items, misc, wsum, &result);
    if (tid == 0) { cutoff[2 * n] = cpos; cutoff[2 * n + 1] = cneg; }
}

// ============ k_final: class from preclass+winners, cutoffs, best_gt recompute, outputs ========
__global__ void __launch_bounds__(256) k_final(const float4* __restrict__ anchors4,
                                               const float4* __restrict__ gts4,
                                               const u32* __restrict__ preclass32,
                                               const int* __restrict__ wnr_g,
                                               const float4* __restrict__ rpos4,
                                               const float4* __restrict__ rneg4,
                                               const u64* __restrict__ cutoff,
                                               float4* __restrict__ out_classes4,
                                               float4* __restrict__ out_deltas) {
    __shared__ float4 gbox[T_N];
    __shared__ float gars[T_N];
    __shared__ int wnrs[T_N];
    int n = blockIdx.y, bx = blockIdx.x, tid = threadIdx.x;
    if (tid < T_N) {
        float4 gb = gts4[n * T_N + tid];
        gbox[tid] = gb;
        {
#pragma clang fp contract(off)
            gars[tid] = (gb.z - gb.x) * (gb.w - gb.y);
        }
        wnrs[tid] = wnr_g[n * T_N + tid];
    }
    __syncthreads();

    size_t gi4 = ((size_t)n * A_N) / 4 + bx * 256 + tid;
    u32 pcw = preclass32[gi4];
    float4 rp = rpos4[gi4];
    float4 rn = rneg4[gi4];
    float rpv[4] = {rp.x, rp.y, rp.z, rp.w};
    float rnv[4] = {rn.x, rn.y, rn.z, rn.w};
    int a0 = (bx * 256 + tid) * 4;
    u64 cp = cutoff[2 * n], cn = cutoff[2 * n + 1];

    u32 marked = 0;
#pragma unroll
    for (int t = 0; t < T_N; t++) {
        u32 d = (u32)(wnrs[t] - a0);
        if (d < 4u) marked |= 1u << d;
    }

    float fcv[4];
#pragma unroll
    for (int j = 0; j < 4; j++) {
        int c = (int)(signed char)((pcw >> (8 * j)) & 0xFF);
        if ((marked >> j) & 1) c = 1;   // winner overrides 0/-1 (>=0.7 already 1)
        int a = a0 + j;
        int fc = -1;
        if (c == 1) {
            u64 p = ((u64)__float_as_uint(rpv[j]) << 32) | (u32)a;
            fc = (p < cp) ? 1 : -1;
        } else if (c == 0) {
            u64 p = ((u64)__float_as_uint(rnv[j]) << 32) | (u32)a;
            fc = (p < cn) ? 0 : -1;
        }
        fcv[j] = (float)fc;

        float4 d = make_float4(0.f, 0.f, 0.f, 0.f);
        if (fc == 1) {
            float4 ab = anchors4[(size_t)n * A_N + a];
            float ay1 = ab.x, ax1 = ab.y, ay2 = ab.z, ax2 = ab.w;
            bool inb = (ay1 >= 0.f) && (ax1 >= 0.f) && (ay2 <= 1.f) && (ax2 <= 1.f);
            if (!inb) { ay1 = ax1 = ay2 = ax2 = 0.f; }
            float a_area;
            {
#pragma clang fp contract(off)
                a_area = (ay2 - ay1) * (ax2 - ax1);
            }
            // exact best_gt: strict > keeps FIRST max index == jnp.argmax semantics
            float vm = 0.f; int jb = 0;
            for (int t = 0; t < T_N; t++) {
                float4 gb = gbox[t];
                float v = iou_one(ay1, ax1, ay2, ax2, a_area, gb.x, gb.y, gb.z, gb.w, gars[t]);
                bool g = v > vm;
                vm = g ? v : vm;
                jb = g ? t : jb;
            }
            float4 gb = gbox[jb];
            float ah = ay2 - ay1, aw = ax2 - ax1;
            float acy = ay1 + 0.5f * ah, acx = ax1 + 0.5f * aw;
            float gh = gb.z - gb.x, gw = gb.w - gb.y;
            float gcy = gb.x + 0.5f * gh, gcx = gb.y + 0.5f * gw;
            float ah_s = ah > 0.f ? ah : 1.f, aw_s = aw > 0.f ? aw : 1.f;
            float gh_s = gh > 0.f ? gh : 1.f, gw_s = gw > 0.f ? gw : 1.f;
            d.x = (gcy - acy) / ah_s;
            d.y = (gcx - acx) / aw_s;
            d.z = logf(gh_s / ah_s);
            d.w = logf(gw_s / aw_s);
        }
        out_deltas[(size_t)n * A_N + a] = d;
    }
    out_classes4[gi4] = make_float4(fcv[0], fcv[1], fcv[2], fcv[3]);
}

extern "C" void kernel_launch(void* const* d_in, const int* in_sizes, int n_in,
                              void* d_out, int out_size, void* d_ws, size_t ws_size,
                              hipStream_t stream) {
    const float* anchors = (const float*)d_in[0];
    const float* gts     = (const float*)d_in[1];
    const float* rpos    = (const float*)d_in[2];
    const float* rneg    = (const float*)d_in[3];

    char* p = (char*)d_ws;
    u64* cutoff   = (u64*)p;  p += 2 * N_B * sizeof(u64);
    u64* colpart  = (u64*)p;  p += (size_t)N_B * T_N * GBLK * sizeof(u64);     // 512 KB
    u64* pos_list = (u64*)p;  p += (size_t)N_B * GBLK * SEG * sizeof(u64);     // 8 MB
    u64* neg_list = (u64*)p;  p += (size_t)N_B * GBLK * SEG * sizeof(u64);     // 8 MB
    unsigned char* preclass = (unsigned char*)p; p += (size_t)N_B * A_N;       // 1 MB
    int* bcp  = (int*)p;  p += N_B * GBLK * sizeof(int);
    int* bcn  = (int*)p;  p += N_B * GBLK * sizeof(int);
    int* wnr  = (int*)p;  p += N_B * T_N * sizeof(int);

    float* out_classes = (float*)d_out;
    float4* out_deltas = (float4*)(out_classes + (size_t)N_B * A_N);

    k_main<<<dim3(GBLK, N_B), 256, 0, stream>>>(
        (const float4*)anchors, (const float4*)gts, rpos, rneg,
        preclass, colpart, pos_list, neg_list, bcp, bcn);
    k_select<<<N_B, 256, 0, stream>>>(pos_list, neg_list, bcp, bcn, colpart,
                                      preclass, rpos, wnr, cutoff);
    k_final<<<dim3(GBLK, N_B), 256, 0, stream>>>(
        (const float4*)anchors, (const float4*)gts, (const u32*)preclass, wnr,
        (const float4*)rpos, (const float4*)rneg, cutoff,
        (float4*)out_classes, out_deltas);
}

// Round 7
// 176.436 us; speedup vs baseline: 2.3992x; 2.3992x over previous
//
#include <hip/hip_runtime.h>
#include <stdint.h>

#define N_B 8
#define A_N 131072
#define T_N 64
#define NUM_TRAIN 256
#define NEG_TAU 0.05f
#define ITEM_CAP 1024
#define APT 4
#define GBLK 128                   // k_main/k_final blocks per batch
#define SEG 1024                   // candidate segment per block (= anchors per block)

typedef unsigned long long u64;
typedef unsigned int u32;

// IoU exactly matching the reference op sequence (no FMA contraction).
__device__ __forceinline__ float iou_one(float ay1, float ax1, float ay2, float ax2,
                                         float a_area, float gy1, float gx1, float gy2,
                                         float gx2, float g_area) {
#pragma clang fp contract(off)
    float ih = fmaxf(fminf(ay2, gy2) - fmaxf(ay1, gy1), 0.0f);
    float iw = fmaxf(fminf(ax2, gx2) - fmaxf(ax1, gx1), 0.0f);
    float inter = ih * iw;
    float uni = (a_area + g_area) - inter;
    return uni > 0.0f ? inter / uni : 0.0f;
}

// ============ k_main: IoU pass + preclass + column partials + candidate segments ============
__global__ void __launch_bounds__(256, 4) k_main(const float4* __restrict__ anchors4,
                                                 const float4* __restrict__ gts4,
                                                 const float* __restrict__ rpos,
                                                 const float* __restrict__ rneg,
                                                 unsigned char* __restrict__ preclass,
                                                 u64* __restrict__ colpart,
                                                 u64* __restrict__ pos_list,
                                                 u64* __restrict__ neg_list,
                                                 int* __restrict__ bcp, int* __restrict__ bcn) {
    __shared__ float4 gbox[T_N];
    __shared__ float gars[T_N];
    __shared__ u64 cmax[T_N];
    __shared__ int lp, ln;
    int n = blockIdx.y, bx = blockIdx.x, tid = threadIdx.x, lane = tid & 63;
    int a0 = bx * SEG + tid;
    size_t nA = (size_t)n * A_N;

    if (tid < T_N) {
        float4 gb = gts4[n * T_N + tid];
        gbox[tid] = gb;
        {
#pragma clang fp contract(off)
            gars[tid] = (gb.z - gb.x) * (gb.w - gb.y);
        }
        cmax[tid] = 0;   // any pack (v<<32)|~a is > 0
    }
    if (tid == 0) { lp = 0; ln = 0; }
    __syncthreads();

    float ay1[APT], ax1[APT], ay2[APT], ax2[APT], aar[APT], vmax[APT];
#pragma unroll
    for (int k = 0; k < APT; k++) {
        float4 ab = anchors4[nA + a0 + k * 256];
        float y1 = ab.x, x1 = ab.y, y2 = ab.z, x2 = ab.w;
        bool inb = (y1 >= 0.f) && (x1 >= 0.f) && (y2 <= 1.f) && (x2 <= 1.f);
        if (!inb) { y1 = x1 = y2 = x2 = 0.f; }
        ay1[k] = y1; ax1[k] = x1; ay2[k] = y2; ax2[k] = x2;
        {
#pragma clang fp contract(off)
            aar[k] = (y2 - y1) * (x2 - x1);
        }
        vmax[k] = 0.f;
    }

#pragma unroll 4
    for (int jj = 0; jj < T_N; jj++) {
        int j = (lane + jj) & (T_N - 1);   // lane-staggered: distinct cmax[j] per lane
        float4 gb = gbox[j];
        float gar = gars[j];
        // k=0 seeds the per-thread column winner; strict > keeps smallest k (= smallest anchor)
        float vb = iou_one(ay1[0], ax1[0], ay2[0], ax2[0], aar[0], gb.x, gb.y, gb.z, gb.w, gar);
        vmax[0] = fmaxf(vmax[0], vb);
        int kb = 0;
#pragma unroll
        for (int k = 1; k < APT; k++) {
            float v = iou_one(ay1[k], ax1[k], ay2[k], ax2[k], aar[k], gb.x, gb.y, gb.z, gb.w, gar);
            vmax[k] = fmaxf(vmax[k], v);
            if (v > vb) { vb = v; kb = k; }
        }
        u64 pk = ((u64)__float_as_uint(vb) << 32) | (u32)(~(u32)(a0 + (kb << 8)));
        atomicMax(&cmax[j], pk);   // fire-and-forget, no same-address contention in-wave
    }

    size_t segbase = ((size_t)(n * GBLK + bx)) << 10;
#pragma unroll
    for (int k = 0; k < APT; k++) {
        int a = a0 + k * 256;
        float vm = vmax[k];
        int c0 = (vm < 0.3f) ? 0 : ((vm >= 0.7f) ? 1 : -1);
        preclass[nA + a] = (unsigned char)(signed char)c0;
        if (c0 == 1) {
            int s = atomicAdd(&lp, 1);
            pos_list[segbase + s] = ((u64)__float_as_uint(rpos[nA + a]) << 32) | (u32)a;
        } else if (c0 == 0) {
            float r = rneg[nA + a];
            if (r < NEG_TAU) {
                int s = atomicAdd(&ln, 1);
                neg_list[segbase + s] = ((u64)__float_as_uint(r) << 32) | (u32)a;
            }
        }
    }
    __syncthreads();
    if (tid < T_N) colpart[(size_t)((n << 6) + tid) * GBLK + bx] = cmax[tid];
    if (tid == 0) { bcp[n * GBLK + bx] = lp; bcn[n * GBLK + bx] = ln; }
}

// ============ exact k-th smallest: 2 threads/segment, 16B chunks, 1-ahead prefetch ============
// exbm (optional): 1 bit per anchor, excluded if set. Returns ovf_all if k >= surviving total.
__device__ u64 select_kth2(const u64* lists, const int* scnt,
                           const u64* extras, int ecnt, const u32* exbm,
                           int k, float scale, u64 ovf_all,
                           int* hist, u64* items, int* misc, int* wsum, u64* result) {
    int tid = threadIdx.x, lane = tid & 63, wid = tid >> 6;
    hist[tid] = 0;
    if (tid == 0) { misc[0] = 0; *result = ovf_all; }
    __syncthreads();

    int seg = tid >> 1, half = tid & 1;
    int c = scnt[seg];
    const ulonglong2* b2 = (const ulonglong2*)(lists + ((size_t)seg << 10));
    int nch = (c + 1) >> 1;   // 16B chunks

    // ---- phase 1: histogram ----
    {
        ulonglong2 q;
        if (half < nch) q = b2[half];
        for (int ci = half; ci < nch; ci += 2) {
            ulonglong2 qn;
            if (ci + 2 < nch) qn = b2[ci + 2];   // prefetch next chunk (overlaps with process)
            {
                u64 p = q.x; int a = (int)(u32)p;
                if (!exbm || !((exbm[a >> 5] >> (a & 31)) & 1)) {
                    float v = __uint_as_float((u32)(p >> 32));
                    int bb = (int)(v * scale); bb = bb > 255 ? 255 : bb;
                    atomicAdd(&hist[bb], 1);
                }
            }
            if (2 * ci + 1 < c) {
                u64 p = q.y; int a = (int)(u32)p;
                if (!exbm || !((exbm[a >> 5] >> (a & 31)) & 1)) {
                    float v = __uint_as_float((u32)(p >> 32));
                    int bb = (int)(v * scale); bb = bb > 255 ? 255 : bb;
                    atomicAdd(&hist[bb], 1);
                }
            }
            q = qn;
        }
    }
    for (int i = tid; i < ecnt; i += 256) {
        float v = __uint_as_float((u32)(extras[i] >> 32));
        int bb = (int)(v * scale); bb = bb > 255 ? 255 : bb;
        atomicAdd(&hist[bb], 1);
    }
    __syncthreads();

    // ---- scan histogram, locate k-th bucket ----
    int h = hist[tid], v = h;
#pragma unroll
    for (int d = 1; d < 64; d <<= 1) {
        int t = __shfl_up(v, d, 64);
        if (lane >= d) v += t;
    }
    if (lane == 63) wsum[wid] = v;
    __syncthreads();
    int base = 0;
    for (int w = 0; w < wid; w++) base += wsum[w];
    int total = wsum[0] + wsum[1] + wsum[2] + wsum[3];
    int incl = base + v, exc = incl - h;
    if (k >= exc && k < incl) { misc[1] = tid; misc[2] = exc; }
    __syncthreads();
    if (k >= total) return ovf_all;   // keep-all (uniform across block)
    int b = misc[1], before = misc[2];

    // ---- phase 2: collect boundary bucket ----
    {
        ulonglong2 q;
        if (half < nch) q = b2[half];
        for (int ci = half; ci < nch; ci += 2) {
            ulonglong2 qn;
            if (ci + 2 < nch) qn = b2[ci + 2];
            {
                u64 p = q.x; int a = (int)(u32)p;
                if (!exbm || !((exbm[a >> 5] >> (a & 31)) & 1)) {
                    float vv = __uint_as_float((u32)(p >> 32));
                    int bn = (int)(vv * scale); bn = bn > 255 ? 255 : bn;
                    if (bn == b) { int ix = atomicAdd(&misc[0], 1); if (ix < ITEM_CAP) items[ix] = p; }
                }
            }
            if (2 * ci + 1 < c) {
                u64 p = q.y; int a = (int)(u32)p;
                if (!exbm || !((exbm[a >> 5] >> (a & 31)) & 1)) {
                    float vv = __uint_as_float((u32)(p >> 32));
                    int bn = (int)(vv * scale); bn = bn > 255 ? 255 : bn;
                    if (bn == b) { int ix = atomicAdd(&misc[0], 1); if (ix < ITEM_CAP) items[ix] = p; }
                }
            }
            q = qn;
        }
    }
    for (int i = tid; i < ecnt; i += 256) {
        u64 p = extras[i];
        float vv = __uint_as_float((u32)(p >> 32));
        int bn = (int)(vv * scale); bn = bn > 255 ? 255 : bn;
        if (bn == b) { int ix = atomicAdd(&misc[0], 1); if (ix < ITEM_CAP) items[ix] = p; }
    }
    __syncthreads();
    int m = misc[0]; m = m < ITEM_CAP ? m : ITEM_CAP;
    int target = k - before;
    for (int i = tid; i < m; i += 256) {
        u64 p = items[i];
        int r = 0;
        for (int j = 0; j < m; j++) r += (items[j] < p);
        if (r == target) *result = p;
    }
    __syncthreads();
    u64 res = *result;
    __syncthreads();
    return res;
}

// ============ k_select: colred + winner extras/exclusion-bitmap + both cutoffs ============
__global__ void __launch_bounds__(256) k_select(const u64* __restrict__ pos_list,
                                                const u64* __restrict__ neg_list,
                                                const int* __restrict__ bcp,
                                                const int* __restrict__ bcn,
                                                const u64* __restrict__ colpart,
                                                const unsigned char* __restrict__ preclass,
                                                const float* __restrict__ rpos,
                                                int* __restrict__ wnr_g,
                                                u64* __restrict__ cutoff) {
    __shared__ int sbp[GBLK], sbn[GBLK];
    __shared__ u64 cq[256];
    __shared__ int wnrs[T_N];
    __shared__ u64 extras[T_N];
    __shared__ int hist[256];
    __shared__ u64 items[ITEM_CAP];
    __shared__ u32 exbm[A_N / 32];   // 16 KB: 1 bit per anchor (winner exclusion for negs)
    __shared__ int misc[4];
    __shared__ u64 result;
    __shared__ int wsum[4];
    __shared__ int shr[9];
    int n = blockIdx.x, tid = threadIdx.x, lane = tid & 63, wid = tid >> 6;

    int pv = tid < GBLK ? bcp[n * GBLK + tid] : 0;
    int nv = tid < GBLK ? bcn[n * GBLK + tid] : 0;
    if (tid < GBLK) { sbp[tid] = pv; sbn[tid] = nv; }
#pragma unroll
    for (int off = 32; off > 0; off >>= 1) {
        pv += __shfl_xor(pv, off, 64);
        nv += __shfl_xor(nv, off, 64);
    }
    if (lane == 0) { shr[wid] = pv; shr[4 + wid] = nv; }

#pragma unroll
    for (int i = 0; i < A_N / 32 / 256; i++) exbm[tid + i * 256] = 0;

    // column reduction: thread (t=tid>>2, q=tid&3) reduces 32 block-partials
    {
        int t = tid >> 2, q = tid & 3;
        const u64* cp = colpart + (size_t)((n << 6) + t) * GBLK + q * 32;
        u64 m = 0;
#pragma unroll 8
        for (int i = 0; i < 32; i++) { u64 x = cp[i]; m = x > m ? x : m; }
        cq[tid] = m;
    }
    __syncthreads();
    if (tid < T_N) {
        u64 m = cq[tid * 4];
        u64 x = cq[tid * 4 + 1]; m = x > m ? x : m;
        x = cq[tid * 4 + 2]; m = x > m ? x : m;
        x = cq[tid * 4 + 3]; m = x > m ? x : m;
        int w = (int)(~(u32)(m & 0xFFFFFFFFull));
        wnrs[tid] = w;
        wnr_g[n * T_N + tid] = w;
        atomicOr(&exbm[w >> 5], 1u << (w & 31));
    }
    __syncthreads();
    if (tid < T_N) {   // wave 0: dedup winners, build pos extras (winners not already preclass==1)
        int w = wnrs[tid];
        bool dup = false;
        for (int t2 = 0; t2 < tid; t2++) dup |= (wnrs[t2] == w);
        int pc = (int)(signed char)preclass[(size_t)n * A_N + w];
        bool val = !dup && (pc != 1);
        u64 mask = __ballot(val);
        if (val) {
            int ix = (int)__popcll(mask & ((1ull << lane) - 1));
            extras[ix] = ((u64)__float_as_uint(rpos[(size_t)n * A_N + w]) << 32) | (u32)w;
        }
        if (tid == 0) shr[8] = (int)__popcll(mask);
    }
    __syncthreads();
    int extra_cnt = shr[8];
    int P = shr[0] + shr[1] + shr[2] + shr[3] + extra_cnt;

    u64 cpos = select_kth2(pos_list + (((size_t)n * GBLK) << 10), sbp,
                           extras, extra_cnt, nullptr,
                           NUM_TRAIN / 2, 256.0f, ~0ull,
                           hist, items, misc, wsum, &result);
    int n_pos = P < NUM_TRAIN / 2 ? P : NUM_TRAIN / 2;
    int k_neg = NUM_TRAIN - n_pos;
    u64 cneg = select_kth2(neg_list + (((size_t)n * GBLK) << 10), sbn,
                           nullptr, 0, exbm,
                           k_neg, 256.0f / NEG_TAU, ((u64)__float_as_uint(NEG_TAU) << 32),
                           hist, items, misc, wsum, &result);
    if (tid == 0) { cutoff[2 * n] = cpos; cutoff[2 * n + 1] = cneg; }
}

// ============ k_final: class from preclass + winner bitmap, cutoffs, best_gt, outputs ========
__global__ void __launch_bounds__(256) k_final(const float4* __restrict__ anchors4,
                                               const float4* __restrict__ gts4,
                                               const u32* __restrict__ preclass32,
                                               const int* __restrict__ wnr_g,
                                               const float4* __restrict__ rpos4,
                                               const float4* __restrict__ rneg4,
                                               const u64* __restrict__ cutoff,
                                               float4* __restrict__ out_classes4,
                                               float4* __restrict__ out_deltas) {
    __shared__ float4 gbox[T_N];
    __shared__ float gars[T_N];
    __shared__ u32 wbm[32];   // 1024-bit winner bitmap for this block's anchors
    int n = blockIdx.y, bx = blockIdx.x, tid = threadIdx.x;
    if (tid < 32) wbm[tid] = 0;
    __syncthreads();
    if (tid < T_N) {
        float4 gb = gts4[n * T_N + tid];
        gbox[tid] = gb;
        {
#pragma clang fp contract(off)
            gars[tid] = (gb.z - gb.x) * (gb.w - gb.y);
        }
        int w = wnr_g[n * T_N + tid];
        int d = w - bx * SEG;
        if ((u32)d < (u32)SEG) atomicOr(&wbm[d >> 5], 1u << (d & 31));
    }
    __syncthreads();

    size_t gi4 = ((size_t)n * A_N) / 4 + bx * 256 + tid;
    u32 pcw = preclass32[gi4];
    float4 rp = rpos4[gi4];
    float4 rn = rneg4[gi4];
    float rpv[4] = {rp.x, rp.y, rp.z, rp.w};
    float rnv[4] = {rn.x, rn.y, rn.z, rn.w};
    int a0 = (bx * 256 + tid) * 4;
    u64 cp = cutoff[2 * n], cn = cutoff[2 * n + 1];

    u32 marked = (wbm[tid >> 3] >> ((tid & 7) * 4)) & 0xF;

    float fcv[4];
#pragma unroll
    for (int j = 0; j < 4; j++) {
        int c = (int)(signed char)((pcw >> (8 * j)) & 0xFF);
        if ((marked >> j) & 1) c = 1;   // winner overrides 0/-1 (>=0.7 already 1)
        int a = a0 + j;
        int fc = -1;
        if (c == 1) {
            u64 p = ((u64)__float_as_uint(rpv[j]) << 32) | (u32)a;
            fc = (p < cp) ? 1 : -1;
        } else if (c == 0) {
            u64 p = ((u64)__float_as_uint(rnv[j]) << 32) | (u32)a;
            fc = (p < cn) ? 0 : -1;
        }
        fcv[j] = (float)fc;

        float4 d = make_float4(0.f, 0.f, 0.f, 0.f);
        if (fc == 1) {
            float4 ab = anchors4[(size_t)n * A_N + a];
            float ay1 = ab.x, ax1 = ab.y, ay2 = ab.z, ax2 = ab.w;
            bool inb = (ay1 >= 0.f) && (ax1 >= 0.f) && (ay2 <= 1.f) && (ax2 <= 1.f);
            if (!inb) { ay1 = ax1 = ay2 = ax2 = 0.f; }
            float a_area;
            {
#pragma clang fp contract(off)
                a_area = (ay2 - ay1) * (ax2 - ax1);
            }
            // exact best_gt: strict > keeps FIRST max index == jnp.argmax semantics
            float vm = 0.f; int jb = 0;
            for (int t = 0; t < T_N; t++) {
                float4 gb = gbox[t];
                float v = iou_one(ay1, ax1, ay2, ax2, a_area, gb.x, gb.y, gb.z, gb.w, gars[t]);
                bool g = v > vm;
                vm = g ? v : vm;
                jb = g ? t : jb;
            }
            float4 gb = gbox[jb];
            float ah = ay2 - ay1, aw = ax2 - ax1;
            float acy = ay1 + 0.5f * ah, acx = ax1 + 0.5f * aw;
            float gh = gb.z - gb.x, gw = gb.w - gb.y;
            float gcy = gb.x + 0.5f * gh, gcx = gb.y + 0.5f * gw;
            float ah_s = ah > 0.f ? ah : 1.f, aw_s = aw > 0.f ? aw : 1.f;
            float gh_s = gh > 0.f ? gh : 1.f, gw_s = gw > 0.f ? gw : 1.f;
            d.x = (gcy - acy) / ah_s;
            d.y = (gcx - acx) / aw_s;
            d.z = logf(gh_s / ah_s);
            d.w = logf(gw_s / aw_s);
        }
        out_deltas[(size_t)n * A_N + a] = d;
    }
    out_classes4[gi4] = make_float4(fcv[0], fcv[1], fcv[2], fcv[3]);
}

extern "C" void kernel_launch(void* const* d_in, const int* in_sizes, int n_in,
                              void* d_out, int out_size, void* d_ws, size_t ws_size,
                              hipStream_t stream) {
    const float* anchors = (const float*)d_in[0];
    const float* gts     = (const float*)d_in[1];
    const float* rpos    = (const float*)d_in[2];
    const float* rneg    = (const float*)d_in[3];

    char* p = (char*)d_ws;
    u64* cutoff   = (u64*)p;  p += 2 * N_B * sizeof(u64);
    u64* colpart  = (u64*)p;  p += (size_t)N_B * T_N * GBLK * sizeof(u64);     // 512 KB
    u64* pos_list = (u64*)p;  p += (size_t)N_B * GBLK * SEG * sizeof(u64);     // 8 MB
    u64* neg_list = (u64*)p;  p += (size_t)N_B * GBLK * SEG * sizeof(u64);     // 8 MB
    unsigned char* preclass = (unsigned char*)p; p += (size_t)N_B * A_N;       // 1 MB
    int* bcp  = (int*)p;  p += N_B * GBLK * sizeof(int);
    int* bcn  = (int*)p;  p += N_B * GBLK * sizeof(int);
    int* wnr  = (int*)p;  p += N_B * T_N * sizeof(int);

    float* out_classes = (float*)d_out;
    float4* out_deltas = (float4*)(out_classes + (size_t)N_B * A_N);

    k_main<<<dim3(GBLK, N_B), 256, 0, stream>>>(
        (const float4*)anchors, (const float4*)gts, rpos, rneg,
        preclass, colpart, pos_list, neg_list, bcp, bcn);
    k_select<<<N_B, 256, 0, stream>>>(pos_list, neg_list, bcp, bcn, colpart,
                                      preclass, rpos, wnr, cutoff);
    k_final<<<dim3(GBLK, N_B), 256, 0, stream>>>(
        (const float4*)anchors, (const float4*)gts, (const u32*)preclass, wnr,
        (const float4*)rpos, (const float4*)rneg, cutoff,
        (float4*)out_classes, out_deltas);
}